// Round 4
// baseline (2138.670 us; speedup 1.0000x reference)
//
#include <hip/hip_runtime.h>
#include <cmath>

// CustomRNNCell: h_{t+1} = tanh(h_t @ W_h^T + b_h + x_t @ W_x^T + b_x)
// B=64, T=512, H=I=1024. Output: h_final [64,1024] fp32.
//
// Phase 1: xp[t][b][j] = x @ W_x^T + (b_x + b_h)   (bf16 MFMA GEMM, fp32 out)
// Phase 2 (R8): block-cooperative h consumption.
//   - 64 blocks x 256 threads (4 waves): 4 batch-groups x 16 j-blocks (64 j).
//   - Wave w: 16 j, W_h rows in 128 VGPRs (A-frags, loaded once; R7-proven
//     fragment layout, but half the register footprint -> no AGPR pressure).
//   - Per step the BLOCK pulls group-h once (32 KB; 8 KB per wave as 16 u64
//     coherent loads), stages to LDS (linear), barrier, all 4 waves MFMA
//     from LDS. Per-wave IF pull: 32 KB -> 8 KB. Aggregate: 8 MB -> 2 MB.
//   - Flags: 16 block-flags per group packed in ONE 64-B line; poll is a
//     single coalesced line load (vs R6's 64-line gather per iteration).
//   - Producer: 4 waves store packed u64 h, vmcnt(0), __syncthreads, tid0
//     publishes block flag. Ring layout + 2-slot parity identical to
//     validated R6 (producer gj = jb*4 + w).

#define Bsz 64
#define Tsz 512
#define Hsz 1024

typedef float  f32x4 __attribute__((ext_vector_type(4)));
typedef short  s16x8 __attribute__((ext_vector_type(8)));

__device__ __forceinline__ unsigned short f2bf(float f) {
  unsigned u = __float_as_uint(f);
  u += 0x7fff + ((u >> 16) & 1);   // round-to-nearest-even (finite inputs)
  return (unsigned short)(u >> 16);
}

__device__ __forceinline__ void pack8(unsigned short* d, float4 v0, float4 v1) {
  d[0] = f2bf(v0.x); d[1] = f2bf(v0.y); d[2] = f2bf(v0.z); d[3] = f2bf(v0.w);
  d[4] = f2bf(v1.x); d[5] = f2bf(v1.y); d[6] = f2bf(v1.z); d[7] = f2bf(v1.w);
}

__device__ __forceinline__ float fast_tanh(float x) {
  float e = __expf(2.0f * x);
  return 1.0f - 2.0f / (e + 1.0f);
}

// ---------------- Phase 1: xp GEMM (unchanged, validated) ----------------
__global__ __launch_bounds__(256) void xp_gemm_kernel(
    const float* __restrict__ x, const float* __restrict__ Wx,
    const float* __restrict__ bx, const float* __restrict__ bh,
    float* __restrict__ xp) {
  __shared__ unsigned short Al[64 * 32];
  __shared__ unsigned short Bl[64 * 32];

  const int tid  = threadIdx.x;
  const int w    = tid >> 6;
  const int lane = tid & 63;
  const int m    = lane & 15;
  const int q    = lane >> 4;
  const int row0 = blockIdx.x * 64;   // flattened (b*T + t) row base
  const int col0 = blockIdx.y * 64;   // hidden col base

  f32x4 acc[4];
#pragma unroll
  for (int i = 0; i < 4; ++i) acc[i] = (f32x4){0.f, 0.f, 0.f, 0.f};

  const int sr = tid >> 2;
  const int sc = tid & 3;
  const int sw = sc ^ ((sr >> 1) & 3);

  for (int kt = 0; kt < 32; ++kt) {
    const int k0 = kt * 32 + sc * 8;
    {
      const float* p = x + (size_t)(row0 + sr) * 1024 + k0;
      pack8(&Al[sr * 32 + sw * 8], *(const float4*)p, *(const float4*)(p + 4));
    }
    {
      const float* p = Wx + (size_t)(col0 + sr) * 1024 + k0;
      pack8(&Bl[sr * 32 + sw * 8], *(const float4*)p, *(const float4*)(p + 4));
    }
    __syncthreads();
    const int arow = w * 16 + m;
    s16x8 a = *(const s16x8*)&Al[arow * 32 + ((q ^ ((arow >> 1) & 3)) << 3)];
#pragma unroll
    for (int nt = 0; nt < 4; ++nt) {
      const int nrow = nt * 16 + m;
      s16x8 b = *(const s16x8*)&Bl[nrow * 32 + ((q ^ ((nrow >> 1) & 3)) << 3)];
      acc[nt] = __builtin_amdgcn_mfma_f32_16x16x32_bf16(a, b, acc[nt], 0, 0, 0);
    }
    __syncthreads();
  }

#pragma unroll
  for (int nt = 0; nt < 4; ++nt) {
    const int col  = col0 + nt * 16 + m;
    const float bias = bx[col] + bh[col];
#pragma unroll
    for (int r = 0; r < 4; ++r) {
      const int rowg = row0 + w * 16 + q * 4 + r;  // = b*512 + t
      const int b = rowg >> 9;
      const int t = rowg & 511;
      xp[(size_t)t * (Bsz * Hsz) + b * Hsz + col] = acc[nt][r] + bias;
    }
  }
}

// ---------------- Phase 2: block-cooperative flag-gated scan ----------------
// Ring (bf16 units): slot[2] x group[4] x [(k>>3)*128 + b*8 + (k&7)],
// k = hidden 0..1023, b = batch-local 0..15.
// Slot stride 16384 u64 (128 KB), group stride 4096 u64 (32 KB).
// Consumer frag kk, lane(m,q): u64 idx kk*128 + q*32 + m*2 (+1) = 16 B s16x8.
// Producer wave gj = jb*4+w, lane(m,q): u64 idx (gj*2+(q>>1))*32 + m*2 + (q&1),
// hv[0..3] packed low->high.  (Both validated in R6.)
// Flags: u32 word per block, group gb's 16 words = one 64-B line.

__global__ __launch_bounds__(256, 1) void rnn_scan_kernel(
    const float* __restrict__ Wh, const float* __restrict__ xp,
    float* __restrict__ out,
    unsigned long long* __restrict__ ring, unsigned* __restrict__ flags) {
  __shared__ unsigned long long Hl[2][4096];  // 64 KB: 2-slot group-h stage

  const int tid  = threadIdx.x;
  const int w    = tid >> 6;        // wave 0..3
  const int lane = tid & 63;
  const int m    = lane & 15;       // batch-local (B-frag col / C col)
  const int q    = lane >> 4;
  const int gb   = blockIdx.x >> 4; // 0..3  batch group
  const int jb   = blockIdx.x & 15; // 0..15 j-block (64 output cols)
  const int j0   = jb * 64 + w * 16;// this wave's 16 output cols
  const int rb   = gb * 16;

  // W_h rows j0..j0+15 -> 128 VGPRs. A-frag: lane(m,q) holds
  // A[row=m][k = kk*32 + q*8 .. +7]  (validated fragment layout, R7).
  s16x8 wreg[32];
#pragma unroll
  for (int kk = 0; kk < 32; ++kk) {
    const float* p = Wh + (size_t)(j0 + m) * 1024 + kk * 32 + q * 8;
    float4 a = *(const float4*)p, b = *(const float4*)(p + 4);
    s16x8 wv;
    wv[0]=f2bf(a.x); wv[1]=f2bf(a.y); wv[2]=f2bf(a.z); wv[3]=f2bf(a.w);
    wv[4]=f2bf(b.x); wv[5]=f2bf(b.y); wv[6]=f2bf(b.z); wv[7]=f2bf(b.w);
    wreg[kk] = wv;
  }

  unsigned* myflag = flags + gb * 16 + jb;           // one line per group
  const unsigned* pollflag = flags + gb * 16 + (lane & 15);

  unsigned long long* const grp = ring + (size_t)gb * 4096;
  const int gj    = jb * 4 + w;     // producer index 0..63 (R6-compatible)
  const int prod_off = (gj * 2 + (q >> 1)) * 32 + m * 2 + (q & 1);
  const int cons_u64 = q * 32 + m * 2;   // fragment base (u64) for this lane

  for (int t = 0; t < Tsz; ++t) {
    // xp_t for (b = rb+m, j = j0 + q*4 + r) — independent of recurrence
    const float4 xv = *(const float4*)(
        xp + (size_t)t * (Bsz * Hsz) + (size_t)(rb + m) * Hsz + j0 + q * 4);
    const float* xf = (const float*)&xv;
    const int p = t & 1;

    f32x4 acc0 = (f32x4){0.f, 0.f, 0.f, 0.f};
    f32x4 acc1 = (f32x4){0.f, 0.f, 0.f, 0.f};
    f32x4 acc2 = (f32x4){0.f, 0.f, 0.f, 0.f};
    f32x4 acc3 = (f32x4){0.f, 0.f, 0.f, 0.f};

    if (t > 0) {
      const unsigned tg = (unsigned)t;
      // Poll the group's packed flag line (1 coalesced line, all lanes).
      unsigned v = __hip_atomic_load(pollflag, __ATOMIC_RELAXED,
                                     __HIP_MEMORY_SCOPE_AGENT);
      while (!__all((int)(v >= tg))) {
        __builtin_amdgcn_s_sleep(1);
        v = __hip_atomic_load(pollflag, __ATOMIC_RELAXED,
                              __HIP_MEMORY_SCOPE_AGENT);
      }

      // Cooperative pull: wave w fetches u64 [w*1024, w*1024+1024) of the
      // group's 32 KB slot (16 x 512-B coherent loads), stages to LDS.
      const unsigned long long* src =
          grp + (size_t)p * 16384 + w * 1024 + lane;
      unsigned long long d[16];
#pragma unroll
      for (int i = 0; i < 16; ++i)
        d[i] = __hip_atomic_load(src + i * 64, __ATOMIC_RELAXED,
                                 __HIP_MEMORY_SCOPE_AGENT);
#pragma unroll
      for (int i = 0; i < 16; ++i)
        Hl[p][w * 1024 + i * 64 + lane] = d[i];
      __syncthreads();

      // 32 fragments from LDS (linear ds_read_b128), MFMA with W-in-regs.
#pragma unroll
      for (int kk = 0; kk < 32; ++kk) {
        const s16x8 hb = *(const s16x8*)&Hl[p][kk * 128 + cons_u64];
        f32x4& ac = ((kk & 3) == 0) ? acc0 : ((kk & 3) == 1) ? acc1
                   : ((kk & 3) == 2) ? acc2 : acc3;
        ac = __builtin_amdgcn_mfma_f32_16x16x32_bf16(wreg[kk], hb, ac, 0, 0, 0);
      }
    }

    const f32x4 accs = (acc0 + acc1) + (acc2 + acc3);
    float hv[4];
#pragma unroll
    for (int r = 0; r < 4; ++r) hv[r] = fast_tanh(accs[r] + xf[r]);

    if (t == Tsz - 1) {
      *(float4*)&out[(size_t)(rb + m) * Hsz + j0 + q * 4] =
          make_float4(hv[0], hv[1], hv[2], hv[3]);
    } else {
      const unsigned long long s =
          (unsigned long long)f2bf(hv[0])        |
          ((unsigned long long)f2bf(hv[1]) << 16) |
          ((unsigned long long)f2bf(hv[2]) << 32) |
          ((unsigned long long)f2bf(hv[3]) << 48);
      unsigned long long* wb = grp + (size_t)((t + 1) & 1) * 16384;
      __hip_atomic_store(wb + prod_off, s, __ATOMIC_RELAXED,
                         __HIP_MEMORY_SCOPE_AGENT);
      // Drain own stores, sync all 4 waves, then tid0 publishes block flag.
      asm volatile("s_waitcnt vmcnt(0)" ::: "memory");
      __syncthreads();
      if (tid == 0)
        __hip_atomic_store(myflag, (unsigned)(t + 1), __ATOMIC_RELAXED,
                           __HIP_MEMORY_SCOPE_AGENT);
    }
  }
}

extern "C" void kernel_launch(void* const* d_in, const int* in_sizes, int n_in,
                              void* d_out, int out_size, void* d_ws, size_t ws_size,
                              hipStream_t stream) {
  (void)in_sizes; (void)n_in; (void)out_size; (void)ws_size;
  const float* x  = (const float*)d_in[0];  // [64,512,1024]
  const float* Wh = (const float*)d_in[1];  // [1024,1024]
  const float* bh = (const float*)d_in[2];  // [1024]
  const float* Wx = (const float*)d_in[3];  // [1024,1024]
  const float* bx = (const float*)d_in[4];  // [1024]
  float* out = (float*)d_out;               // [64,1024]

  char* ws = (char*)d_ws;
  unsigned*           flags = (unsigned*)ws;                    // 256 B used
  unsigned long long* ring  = (unsigned long long*)(ws + 65536);// 256 KB
  float*              xp    = (float*)(ws + (1 << 20));         // 128 MB

  // only flags need zeroing (step 0 reads no h buffer)
  hipMemsetAsync(d_ws, 0, 16384, stream);

  dim3 g1(Bsz * Tsz / 64, Hsz / 64);
  xp_gemm_kernel<<<g1, dim3(256), 0, stream>>>(x, Wx, bx, bh, xp);
  rnn_scan_kernel<<<dim3(64), dim3(256), 0, stream>>>(Wh, xp, out, ring, flags);
}

// Round 5
// 2130.843 us; speedup vs baseline: 1.0037x; 1.0037x over previous
//
#include <hip/hip_runtime.h>
#include <cmath>

// CustomRNNCell: h_{t+1} = tanh(h_t @ W_h^T + b_h + x_t @ W_x^T + b_x)
// B=64, T=512, H=I=1024. Output: h_final [64,1024] fp32.
//
// Phase 1: xp[t][b][j] = x @ W_x^T + (b_x + b_h)   (bf16 MFMA GEMM, fp32 out)
// Phase 2 (R9): SINGLE-round-trip tag-in-band exchange, block-cooperative.
//   - 64 blocks x 256 threads: 4 batch-groups x 16 j-blocks; wave w owns 16 j
//     with W_h rows in 128 VGPRs (R7/R8-proven A-frag layout).
//   - h exchanged as u32 = (bf16 << 16) | step_tag in a 2-slot ring
//     (slot = t&1, tag = t). Producer: 2 u64 agent-atomic stores, NO drain,
//     NO flag, NO barrier. Consumer: block cooperatively loads its group's
//     tagged 64 KB slot fully coalesced (16 dwordx4/thread, sc0 sc1),
//     validates ALL 64 tags with one accumulated mask + one ballot,
//     retries the whole batch only on failure (rare: waves are lockstepped
//     by the all-to-all), de-tags via v_perm, stages bf16 to LDS, barrier,
//     MFMA (R8's consumer path).
//   - Ring safety under ANY skew: writing tag t+2 into slot t&1 requires all
//     waves produced t+1, which requires all consumed t. Per-u32 tags with
//     u64 store atomicity certify every 8-B unit independently.

#define Bsz 64
#define Tsz 512
#define Hsz 1024

typedef float  f32x4 __attribute__((ext_vector_type(4)));
typedef short  s16x8 __attribute__((ext_vector_type(8)));

__device__ __forceinline__ unsigned short f2bf(float f) {
  unsigned u = __float_as_uint(f);
  u += 0x7fff + ((u >> 16) & 1);   // round-to-nearest-even (finite inputs)
  return (unsigned short)(u >> 16);
}

__device__ __forceinline__ void pack8(unsigned short* d, float4 v0, float4 v1) {
  d[0] = f2bf(v0.x); d[1] = f2bf(v0.y); d[2] = f2bf(v0.z); d[3] = f2bf(v0.w);
  d[4] = f2bf(v1.x); d[5] = f2bf(v1.y); d[6] = f2bf(v1.z); d[7] = f2bf(v1.w);
}

__device__ __forceinline__ float fast_tanh(float x) {
  float e = __expf(2.0f * x);
  return 1.0f - 2.0f / (e + 1.0f);
}

// ---------------- Phase 1: xp GEMM (unchanged, validated) ----------------
__global__ __launch_bounds__(256) void xp_gemm_kernel(
    const float* __restrict__ x, const float* __restrict__ Wx,
    const float* __restrict__ bx, const float* __restrict__ bh,
    float* __restrict__ xp) {
  __shared__ unsigned short Al[64 * 32];
  __shared__ unsigned short Bl[64 * 32];

  const int tid  = threadIdx.x;
  const int w    = tid >> 6;
  const int lane = tid & 63;
  const int m    = lane & 15;
  const int q    = lane >> 4;
  const int row0 = blockIdx.x * 64;   // flattened (b*T + t) row base
  const int col0 = blockIdx.y * 64;   // hidden col base

  f32x4 acc[4];
#pragma unroll
  for (int i = 0; i < 4; ++i) acc[i] = (f32x4){0.f, 0.f, 0.f, 0.f};

  const int sr = tid >> 2;
  const int sc = tid & 3;
  const int sw = sc ^ ((sr >> 1) & 3);

  for (int kt = 0; kt < 32; ++kt) {
    const int k0 = kt * 32 + sc * 8;
    {
      const float* p = x + (size_t)(row0 + sr) * 1024 + k0;
      pack8(&Al[sr * 32 + sw * 8], *(const float4*)p, *(const float4*)(p + 4));
    }
    {
      const float* p = Wx + (size_t)(col0 + sr) * 1024 + k0;
      pack8(&Bl[sr * 32 + sw * 8], *(const float4*)p, *(const float4*)(p + 4));
    }
    __syncthreads();
    const int arow = w * 16 + m;
    s16x8 a = *(const s16x8*)&Al[arow * 32 + ((q ^ ((arow >> 1) & 3)) << 3)];
#pragma unroll
    for (int nt = 0; nt < 4; ++nt) {
      const int nrow = nt * 16 + m;
      s16x8 b = *(const s16x8*)&Bl[nrow * 32 + ((q ^ ((nrow >> 1) & 3)) << 3)];
      acc[nt] = __builtin_amdgcn_mfma_f32_16x16x32_bf16(a, b, acc[nt], 0, 0, 0);
    }
    __syncthreads();
  }

#pragma unroll
  for (int nt = 0; nt < 4; ++nt) {
    const int col  = col0 + nt * 16 + m;
    const float bias = bx[col] + bh[col];
#pragma unroll
    for (int r = 0; r < 4; ++r) {
      const int rowg = row0 + w * 16 + q * 4 + r;  // = b*512 + t
      const int b = rowg >> 9;
      const int t = rowg & 511;
      xp[(size_t)t * (Bsz * Hsz) + b * Hsz + col] = acc[nt][r] + bias;
    }
  }
}

// ---------------- Phase 2: tag-in-band single-RT scan ----------------
// Ring (u32 units, 1:1 with staged bf16 idx): within a 64 KB slot-group
// region, idx(k,b) = (k>>5)*512 + ((k>>3)&3)*128 + b*8 + (k&7).
// Region byte offset = ((slot*4)+gb)*65536; slot = tag&1.
// Consumer frag kk, lane(m,q): bf16 idx kk*512+q*128+m*8 -> Hl u64
//   idx kk*128 + q*32 + m*2 (16 B = s16x8).  [R8-validated]
// Producer block jb, wave w, lane(m,q): j = jb*64+w*16+q*4+r, b=m:
//   u32 base = (jb*2+(w>>1))*512 + ((w&1)*2+(q>>1))*128 + m*8 + (q&1)*4,
//   u64 store idx = base/2, pairs (r0,r1),(r2,r3).  [verified k=100,1023]

#define LOAD16(PSRC)                                                          \
  do {                                                                        \
    unsigned voff_ = tid * 32;                                                \
    asm volatile(                                                             \
      "global_load_dwordx4 %0, %16, %17 sc0 sc1\n\t"                          \
      "global_load_dwordx4 %1, %16, %17 offset:16 sc0 sc1\n\t"                \
      "v_add_u32 %16, 0x2000, %16\n\t"                                        \
      "global_load_dwordx4 %2, %16, %17 sc0 sc1\n\t"                          \
      "global_load_dwordx4 %3, %16, %17 offset:16 sc0 sc1\n\t"                \
      "v_add_u32 %16, 0x2000, %16\n\t"                                        \
      "global_load_dwordx4 %4, %16, %17 sc0 sc1\n\t"                          \
      "global_load_dwordx4 %5, %16, %17 offset:16 sc0 sc1\n\t"                \
      "v_add_u32 %16, 0x2000, %16\n\t"                                        \
      "global_load_dwordx4 %6, %16, %17 sc0 sc1\n\t"                          \
      "global_load_dwordx4 %7, %16, %17 offset:16 sc0 sc1\n\t"                \
      "v_add_u32 %16, 0x2000, %16\n\t"                                        \
      "global_load_dwordx4 %8, %16, %17 sc0 sc1\n\t"                          \
      "global_load_dwordx4 %9, %16, %17 offset:16 sc0 sc1\n\t"                \
      "v_add_u32 %16, 0x2000, %16\n\t"                                        \
      "global_load_dwordx4 %10, %16, %17 sc0 sc1\n\t"                         \
      "global_load_dwordx4 %11, %16, %17 offset:16 sc0 sc1\n\t"               \
      "v_add_u32 %16, 0x2000, %16\n\t"                                        \
      "global_load_dwordx4 %12, %16, %17 sc0 sc1\n\t"                         \
      "global_load_dwordx4 %13, %16, %17 offset:16 sc0 sc1\n\t"               \
      "v_add_u32 %16, 0x2000, %16\n\t"                                        \
      "global_load_dwordx4 %14, %16, %17 sc0 sc1\n\t"                         \
      "global_load_dwordx4 %15, %16, %17 offset:16 sc0 sc1\n\t"               \
      "s_waitcnt vmcnt(0)"                                                    \
      : "=&v"(L0), "=&v"(L1), "=&v"(L2), "=&v"(L3),                           \
        "=&v"(L4), "=&v"(L5), "=&v"(L6), "=&v"(L7),                           \
        "=&v"(L8), "=&v"(L9), "=&v"(LA), "=&v"(LB),                           \
        "=&v"(LC), "=&v"(LD), "=&v"(LE), "=&v"(LF), "+v"(voff_)               \
      : "s"(PSRC)                                                             \
      : "memory");                                                            \
  } while (0)

#define TACC(V) ((V.x ^ tg) | (V.y ^ tg) | (V.z ^ tg) | (V.w ^ tg))

#define STG(j, A, B2)                                                         \
  do {                                                                        \
    uint4 s_;                                                                 \
    s_.x = __builtin_amdgcn_perm(A.y,  A.x,  0x07060302u);                    \
    s_.y = __builtin_amdgcn_perm(A.w,  A.z,  0x07060302u);                    \
    s_.z = __builtin_amdgcn_perm(B2.y, B2.x, 0x07060302u);                    \
    s_.w = __builtin_amdgcn_perm(B2.w, B2.z, 0x07060302u);                    \
    Hs[(j) * 256 + tid] = s_;                                                 \
  } while (0)

__global__ __launch_bounds__(256, 1) void rnn_scan_kernel(
    const float* __restrict__ Wh, const float* __restrict__ xp,
    float* __restrict__ out, unsigned long long* __restrict__ ring) {
  __shared__ unsigned long long Hl[2][4096];  // 2 x 32 KB de-tagged h stage

  const int tid  = threadIdx.x;
  const int w    = tid >> 6;        // wave 0..3
  const int lane = tid & 63;
  const int m    = lane & 15;       // batch-local (B-frag col / C col)
  const int q    = lane >> 4;
  const int gb   = blockIdx.x >> 4; // 0..3  batch group
  const int jb   = blockIdx.x & 15; // 0..15 j-block (64 output cols)
  const int j0   = jb * 64 + w * 16;// this wave's 16 output cols
  const int rb   = gb * 16;

  // W_h rows j0..j0+15 -> 128 VGPRs (validated fragment layout, R7/R8).
  s16x8 wreg[32];
#pragma unroll
  for (int kk = 0; kk < 32; ++kk) {
    const float* p = Wh + (size_t)(j0 + m) * 1024 + kk * 32 + q * 8;
    float4 a = *(const float4*)p, b = *(const float4*)(p + 4);
    s16x8 wv;
    wv[0]=f2bf(a.x); wv[1]=f2bf(a.y); wv[2]=f2bf(a.z); wv[3]=f2bf(a.w);
    wv[4]=f2bf(b.x); wv[5]=f2bf(b.y); wv[6]=f2bf(b.z); wv[7]=f2bf(b.w);
    wreg[kk] = wv;
  }

  const int prod_u64 =
      (jb * 2 + (w >> 1)) * 256 + ((w & 1) * 2 + (q >> 1)) * 64 +
      m * 4 + (q & 1) * 2;
  const int cons_u64 = q * 32 + m * 2;   // frag base in Hl (u64 units)

  for (int t = 0; t < Tsz; ++t) {
    // xp_t for (b = rb+m, j = j0 + q*4 + r) — independent of recurrence
    const float4 xv = *(const float4*)(
        xp + (size_t)t * (Bsz * Hsz) + (size_t)(rb + m) * Hsz + j0 + q * 4);
    const float* xf = (const float*)&xv;
    const int p = t & 1;

    f32x4 acc0 = (f32x4){0.f, 0.f, 0.f, 0.f};
    f32x4 acc1 = (f32x4){0.f, 0.f, 0.f, 0.f};
    f32x4 acc2 = (f32x4){0.f, 0.f, 0.f, 0.f};
    f32x4 acc3 = (f32x4){0.f, 0.f, 0.f, 0.f};

    if (t > 0) {
      const unsigned tg = (unsigned)t;
      const unsigned long long srcp =
          (unsigned long long)(const char*)ring +
          (unsigned)(((p * 4) + gb) << 16);

      uint4 L0, L1, L2, L3, L4, L5, L6, L7;
      uint4 L8, L9, LA, LB, LC, LD, LE, LF;
      LOAD16(srcp);
      for (;;) {
        unsigned d_ = TACC(L0) | TACC(L1) | TACC(L2) | TACC(L3);
        d_ |= TACC(L4) | TACC(L5) | TACC(L6) | TACC(L7);
        d_ |= TACC(L8) | TACC(L9) | TACC(LA) | TACC(LB);
        d_ |= TACC(LC) | TACC(LD) | TACC(LE) | TACC(LF);
        if (__all((int)((d_ & 0xFFFFu) == 0u))) break;
        __builtin_amdgcn_s_sleep(1);
        LOAD16(srcp);
      }

      // De-tag + stage bf16 to LDS (coalesced: per wave lanes write
      // contiguous 16-B chunks -> conflict-free ds_write_b128).
      uint4* Hs = (uint4*)&Hl[p][0];
      STG(0, L0, L1); STG(1, L2, L3); STG(2, L4, L5); STG(3, L6, L7);
      STG(4, L8, L9); STG(5, LA, LB); STG(6, LC, LD); STG(7, LE, LF);
      __syncthreads();

      // 32 fragments from LDS (linear ds_read_b128), MFMA with W-in-regs.
#pragma unroll
      for (int kk = 0; kk < 32; ++kk) {
        const s16x8 hb = *(const s16x8*)&Hl[p][kk * 128 + cons_u64];
        f32x4& ac = ((kk & 3) == 0) ? acc0 : ((kk & 3) == 1) ? acc1
                   : ((kk & 3) == 2) ? acc2 : acc3;
        ac = __builtin_amdgcn_mfma_f32_16x16x32_bf16(wreg[kk], hb, ac, 0, 0, 0);
      }
    }

    const f32x4 accs = (acc0 + acc1) + (acc2 + acc3);
    float hv[4];
#pragma unroll
    for (int r = 0; r < 4; ++r) hv[r] = fast_tanh(accs[r] + xf[r]);

    if (t == Tsz - 1) {
      *(float4*)&out[(size_t)(rb + m) * Hsz + j0 + q * 4] =
          make_float4(hv[0], hv[1], hv[2], hv[3]);
    } else {
      // Self-certifying stores, tag = t+1. No drain, no flag, no barrier.
      const unsigned tg1 = (unsigned)(t + 1);
      const unsigned u0 = tg1 | ((unsigned)f2bf(hv[0]) << 16);
      const unsigned u1 = tg1 | ((unsigned)f2bf(hv[1]) << 16);
      const unsigned u2 = tg1 | ((unsigned)f2bf(hv[2]) << 16);
      const unsigned u3 = tg1 | ((unsigned)f2bf(hv[3]) << 16);
      const unsigned long long s0 = u0 | ((unsigned long long)u1 << 32);
      const unsigned long long s1 = u2 | ((unsigned long long)u3 << 32);
      unsigned long long* wb =
          ring + (size_t)(((t + 1) & 1) * 4 + gb) * 8192 + prod_u64;
      __hip_atomic_store(wb,     s0, __ATOMIC_RELAXED, __HIP_MEMORY_SCOPE_AGENT);
      __hip_atomic_store(wb + 1, s1, __ATOMIC_RELAXED, __HIP_MEMORY_SCOPE_AGENT);
    }
  }
}

extern "C" void kernel_launch(void* const* d_in, const int* in_sizes, int n_in,
                              void* d_out, int out_size, void* d_ws, size_t ws_size,
                              hipStream_t stream) {
  (void)in_sizes; (void)n_in; (void)out_size; (void)ws_size;
  const float* x  = (const float*)d_in[0];  // [64,512,1024]
  const float* Wh = (const float*)d_in[1];  // [1024,1024]
  const float* bh = (const float*)d_in[2];  // [1024]
  const float* Wx = (const float*)d_in[3];  // [1024,1024]
  const float* bx = (const float*)d_in[4];  // [1024]
  float* out = (float*)d_out;               // [64,1024]

  char* ws = (char*)d_ws;
  unsigned long long* ring = (unsigned long long*)ws;   // 512 KB, 2-slot ring
  float*              xp   = (float*)(ws + (1 << 20));  // 128 MB

  // ring tags must start < 1 (step-1 consumers validate tag==1)
  hipMemsetAsync(d_ws, 0, 524288, stream);

  dim3 g1(Bsz * Tsz / 64, Hsz / 64);
  xp_gemm_kernel<<<g1, dim3(256), 0, stream>>>(x, Wx, bx, bh, xp);
  rnn_scan_kernel<<<dim3(64), dim3(256), 0, stream>>>(Wh, xp, out, ring);
}